// Round 2
// baseline (1758.781 us; speedup 1.0000x reference)
//
#include <hip/hip_runtime.h>

typedef __attribute__((ext_vector_type(8))) short bf16x8;
typedef __attribute__((ext_vector_type(4))) float f32x4;
typedef __attribute__((ext_vector_type(2))) unsigned int u32x2;
typedef __attribute__((ext_vector_type(4))) unsigned int u32x4;

__device__ __forceinline__ unsigned cvt_pk_bf16(float lo, float hi){
  unsigned r; asm("v_cvt_pk_bf16_f32 %0, %1, %2" : "=v"(r) : "v"(lo), "v"(hi)); return r;
}
// sigmoid(x) = 1/(1+2^(-x*log2e)); inf-safe at both ends (rcp(inf)=0).
__device__ __forceinline__ float sig_f(float x){
  return __builtin_amdgcn_rcpf(1.f + __builtin_amdgcn_exp2f(-1.442695040888963f*x));
}
// tanh(x) = 1 - 2/(1+2^(2x*log2e)); inf-safe.
__device__ __forceinline__ float tanh_f(float x){
  return 1.f - 2.f*__builtin_amdgcn_rcpf(1.f + __builtin_amdgcn_exp2f(2.885390081777927f*x));
}

// ---------------- prologue 1: embproj[dir][tok][m] = emb[tok]@Wx_dir + b_dir --------------
__global__ void embproj_kernel(const float* __restrict__ emb,
                               const float* __restrict__ Wx_f, const float* __restrict__ b_f,
                               const float* __restrict__ Wx_b, const float* __restrict__ b_b,
                               float* __restrict__ embproj){
  const int blk = blockIdx.x;              // 1024 blocks = 2 dir * 128 tok * 4 chunks
  const int dir = blk >> 9;
  const int tok = (blk >> 2) & 127;
  const int m   = (blk & 3)*256 + threadIdx.x;
  const float* Wx = dir ? Wx_b : Wx_f;
  const float* bb = dir ? b_b  : b_f;
  __shared__ float es[128];
  if (threadIdx.x < 128) es[threadIdx.x] = emb[tok*128 + threadIdx.x];
  __syncthreads();
  float acc = bb[m];
  #pragma unroll 4
  for (int e = 0; e < 128; e++) acc = fmaf(es[e], Wx[e*1024 + m], acc);
  embproj[(dir*128 + tok)*1024 + m] = acc;
}

// ---------------- prologue 2: pack Wh^T into MFMA A-fragment order (bf16) -----------------
// frag layout: [dir][mf(64)][kb(8)][lane(64)] x 16B; lane: m = mf*16+(l&15),
// k-slot j: k = kb*32 + (l>>4)*4 + (j&3) + 16*(j>>2)   (A and B use the same map)
__global__ void whpack_kernel(const float* __restrict__ Wh_f, const float* __restrict__ Wh_b,
                              u32x4* __restrict__ whpack){
  const int t = blockIdx.x*256 + threadIdx.x;  // 65536 threads
  const int lane = t & 63;
  const int kb   = (t >> 6) & 7;
  const int mf   = (t >> 9) & 63;
  const int dir  = t >> 15;
  const float* Wh = dir ? Wh_b : Wh_f;  // [256 k][1024 m]
  const int m = mf*16 + (lane & 15);
  const int kbase = kb*32 + ((lane >> 4) << 2);
  u32x4 o;
  #pragma unroll
  for (int p = 0; p < 4; p++){           // u32 p holds slots j=2p, 2p+1
    const int k0 = kbase + (p & 1)*2 + (p >> 1)*16;
    unsigned pk = cvt_pk_bf16(Wh[k0*1024 + m], Wh[(k0+1)*1024 + m]);
    if (p == 0) o.x = pk; else if (p == 1) o.y = pk; else if (p == 2) o.z = pk; else o.w = pk;
  }
  whpack[t] = o;
}

// ---------------- main: persistent per-block LSTM over 128 steps --------------------------
// grid 128: blocks 0..63 forward rows r0=32*bid, 64..127 backward. 512 thr = 8 waves,
// wave w owns units [32w,32w+32) i.e. gate rows {g*256+32w..+32} for g=i,f,g,o.
__global__ __launch_bounds__(512, 2) void lstm_kernel(
    const int* __restrict__ tokens, const float* __restrict__ embproj,
    const bf16x8* __restrict__ whpack, float* __restrict__ out)
{
  const int bid = blockIdx.x;
  const int dir = bid >> 6;
  const int r0  = (bid & 63) << 5;
  const int tid = threadIdx.x;
  const int w   = tid >> 6;
  const int l   = tid & 63;
  const int l15 = l & 15;
  const int lg  = l >> 4;

  const float*  ep = embproj + dir*131072;      // [128][1024]
  const bf16x8* wp = whpack + dir*32768 + l;    // + lane

  // h double-buffer in B-fragment order: [buf][cf][kb][lane][4xu32]
  __shared__ __align__(16) unsigned hbuf[2][2][8][64][4];
  {
    unsigned* hz = &hbuf[0][0][0][0][0];
    for (int i = tid; i < 4096; i += 512) hz[i] = 0u;
  }
  __syncthreads();

  f32x4 c[2][2];   // [cf][q] : c for (b=cf*16+l15, u=32w+16q+4lg+reg)
  f32x4 hf[2][2];
  #pragma unroll
  for (int a = 0; a < 2; a++)
    #pragma unroll
    for (int b2 = 0; b2 < 2; b2++){ c[a][b2] = {0.f,0.f,0.f,0.f}; hf[a][b2] = {0.f,0.f,0.f,0.f}; }

  for (int t = 0; t < 128; t++){
    const int tcol = dir ? (127 - t) : t;
    const int tok0 = tokens[(r0 + l15)*128 + tcol];
    const int tok1 = tokens[(r0 + 16 + l15)*128 + tcol];
    const float* g0 = ep + tok0*1024 + lg*4;
    const float* g1 = ep + tok1*1024 + lg*4;

    // init acc with xz (MFMA C-in): acc[g][q][cf], D row = m-within-frag, col = batch
    f32x4 acc[4][2][2];
    #pragma unroll
    for (int g = 0; g < 4; g++)
      #pragma unroll
      for (int q = 0; q < 2; q++){
        const int m0 = g*256 + w*32 + q*16;
        acc[g][q][0] = *(const f32x4*)(g0 + m0);
        acc[g][q][1] = *(const f32x4*)(g1 + m0);
      }

    const int rb = t & 1;
    bf16x8 A[3][8];   // 2-ahead prefetch of weight frags (f = g*2+q)
    bf16x8 B[3][2];
    #pragma unroll
    for (int f = 0; f < 8; f++){
      const int mf = (f >> 1)*16 + w*2 + (f & 1);
      A[0][f] = wp[(mf*8 + 0)*64];
      A[1][f] = wp[(mf*8 + 1)*64];
    }
    #pragma unroll
    for (int cf = 0; cf < 2; cf++){
      B[0][cf] = *(const bf16x8*)&hbuf[rb][cf][0][l][0];
      B[1][cf] = *(const bf16x8*)&hbuf[rb][cf][1][l][0];
    }

    #pragma unroll
    for (int kb = 0; kb < 8; kb++){
      const int cur = kb % 3;
      const int nxt = (kb + 2) % 3;
      if (kb < 6){
        #pragma unroll
        for (int f = 0; f < 8; f++){
          const int mf = (f >> 1)*16 + w*2 + (f & 1);
          A[nxt][f] = wp[(mf*8 + kb + 2)*64];
        }
        B[nxt][0] = *(const bf16x8*)&hbuf[rb][0][kb + 2][l][0];
        B[nxt][1] = *(const bf16x8*)&hbuf[rb][1][kb + 2][l][0];
      }
      #pragma unroll
      for (int g = 0; g < 4; g++)
        #pragma unroll
        for (int q = 0; q < 2; q++){
          acc[g][q][0] = __builtin_amdgcn_mfma_f32_16x16x32_bf16(A[cur][g*2+q], B[cur][0], acc[g][q][0], 0, 0, 0);
          acc[g][q][1] = __builtin_amdgcn_mfma_f32_16x16x32_bf16(A[cur][g*2+q], B[cur][1], acc[g][q][1], 0, 0, 0);
        }
    }

    // gates + state update; write h (bf16) into next buffer, B-frag-aligned (kb = w)
    #pragma unroll
    for (int cf = 0; cf < 2; cf++)
      #pragma unroll
      for (int q = 0; q < 2; q++){
        f32x4 ci = c[cf][q];
        f32x4 hv;
        #pragma unroll
        for (int r = 0; r < 4; r++){
          const float zi = acc[0][q][cf][r];
          const float zf = acc[1][q][cf][r];
          const float zg = acc[2][q][cf][r];
          const float zo = acc[3][q][cf][r];
          const float cn = sig_f(zf)*ci[r] + sig_f(zi)*tanh_f(zg);
          ci[r] = cn;
          hv[r] = sig_f(zo)*tanh_f(cn);
        }
        c[cf][q]  = ci;
        hf[cf][q] = hv;
        u32x2 pk;
        pk.x = cvt_pk_bf16(hv[0], hv[1]);
        pk.y = cvt_pk_bf16(hv[2], hv[3]);
        *(u32x2*)&hbuf[rb ^ 1][cf][w][l][q*2] = pk;
      }
    __syncthreads();
  }

  // outputs: output[2048][512], fh@1048576, fc@1572864, bh@2097152, bc@2621440
  #pragma unroll
  for (int cf = 0; cf < 2; cf++)
    #pragma unroll
    for (int q = 0; q < 2; q++){
      const int b  = r0 + cf*16 + l15;
      const int u0 = w*32 + q*16 + lg*4;
      *(f32x4*)(out + b*512 + dir*256 + u0)                     = hf[cf][q];
      *(f32x4*)(out + 1048576 + dir*1048576 + b*256 + u0)       = hf[cf][q];
      *(f32x4*)(out + 1572864 + dir*1048576 + b*256 + u0)       = c[cf][q];
    }
}

extern "C" void kernel_launch(void* const* d_in, const int* in_sizes, int n_in,
                              void* d_out, int out_size, void* d_ws, size_t ws_size,
                              hipStream_t stream){
  const int*   tokens = (const int*)  d_in[0];
  const float* emb    = (const float*)d_in[1];
  const float* Wx_f   = (const float*)d_in[2];
  const float* Wh_f   = (const float*)d_in[3];
  const float* b_f    = (const float*)d_in[4];
  const float* Wx_b   = (const float*)d_in[5];
  const float* Wh_b   = (const float*)d_in[6];
  const float* b_b    = (const float*)d_in[7];
  float* out = (float*)d_out;

  // ws: embproj 2*128*1024 f32 (1 MB) | whpack 2*64*8*64 frags * 16B (1 MB)
  float*  embproj = (float*)d_ws;
  u32x4*  whpack  = (u32x4*)(embproj + 262144);

  embproj_kernel<<<1024, 256, 0, stream>>>(emb, Wx_f, b_f, Wx_b, b_b, embproj);
  whpack_kernel<<<256, 256, 0, stream>>>(Wh_f, Wh_b, whpack);
  lstm_kernel<<<128, 512, 0, stream>>>(tokens, embproj, (const bf16x8*)whpack, out);
}

// Round 3
// 932.622 us; speedup vs baseline: 1.8858x; 1.8858x over previous
//
#include <hip/hip_runtime.h>

typedef __attribute__((ext_vector_type(8))) short bf16x8;
typedef __attribute__((ext_vector_type(4))) float f32x4;
typedef __attribute__((ext_vector_type(2))) unsigned int u32x2;
typedef __attribute__((ext_vector_type(4))) unsigned int u32x4;

__device__ __forceinline__ unsigned cvt_pk_bf16(float lo, float hi){
  unsigned r; asm("v_cvt_pk_bf16_f32 %0, %1, %2" : "=v"(r) : "v"(lo), "v"(hi)); return r;
}
// sigmoid(x) = 1/(1+2^(-x*log2e)); inf-safe at both ends (rcp(inf)=0).
__device__ __forceinline__ float sig_f(float x){
  return __builtin_amdgcn_rcpf(1.f + __builtin_amdgcn_exp2f(-1.442695040888963f*x));
}
// tanh(x) = 1 - 2/(1+2^(2x*log2e)); inf-safe.
__device__ __forceinline__ float tanh_f(float x){
  return 1.f - 2.f*__builtin_amdgcn_rcpf(1.f + __builtin_amdgcn_exp2f(2.885390081777927f*x));
}

// ---------------- prologue 1: embproj[dir][tok][m] = emb[tok]@Wx_dir + b_dir --------------
__global__ void embproj_kernel(const float* __restrict__ emb,
                               const float* __restrict__ Wx_f, const float* __restrict__ b_f,
                               const float* __restrict__ Wx_b, const float* __restrict__ b_b,
                               float* __restrict__ embproj){
  const int blk = blockIdx.x;              // 1024 blocks = 2 dir * 128 tok * 4 chunks
  const int dir = blk >> 9;
  const int tok = (blk >> 2) & 127;
  const int m   = (blk & 3)*256 + threadIdx.x;
  const float* Wx = dir ? Wx_b : Wx_f;
  const float* bb = dir ? b_b  : b_f;
  __shared__ float es[128];
  if (threadIdx.x < 128) es[threadIdx.x] = emb[tok*128 + threadIdx.x];
  __syncthreads();
  float acc = bb[m];
  #pragma unroll 4
  for (int e = 0; e < 128; e++) acc = fmaf(es[e], Wx[e*1024 + m], acc);
  embproj[(dir*128 + tok)*1024 + m] = acc;
}

// ---------------- prologue 2: pack Wh^T into MFMA A-fragment order (bf16) -----------------
// frag layout: [dir][mf(64)][kb(8)][lane(64)] x 16B; lane: m = mf*16+(l&15),
// k-slot j: k = kb*32 + (l>>4)*4 + (j&3) + 16*(j>>2)   (A and B use the same map)
__global__ void whpack_kernel(const float* __restrict__ Wh_f, const float* __restrict__ Wh_b,
                              u32x4* __restrict__ whpack){
  const int t = blockIdx.x*256 + threadIdx.x;  // 65536 threads
  const int lane = t & 63;
  const int kb   = (t >> 6) & 7;
  const int mf   = (t >> 9) & 63;
  const int dir  = t >> 15;
  const float* Wh = dir ? Wh_b : Wh_f;  // [256 k][1024 m]
  const int m = mf*16 + (lane & 15);
  const int kbase = kb*32 + ((lane >> 4) << 2);
  u32x4 o;
  #pragma unroll
  for (int p = 0; p < 4; p++){           // u32 p holds slots j=2p, 2p+1
    const int k0 = kbase + (p & 1)*2 + (p >> 1)*16;
    unsigned pk = cvt_pk_bf16(Wh[k0*1024 + m], Wh[(k0+1)*1024 + m]);
    if (p == 0) o.x = pk; else if (p == 1) o.y = pk; else if (p == 2) o.z = pk; else o.w = pk;
  }
  whpack[t] = o;
}

// ---------------- main: persistent LSTM, weights VGPR-resident ----------------------------
// grid 256 = 2 dir * 128 batch-tiles of 16 rows. 1024 thr = 16 waves; wave w owns units
// [16w,16w+16) for all 4 gates -> 4 mf-frags x 8 kb = 32 A-frags = 128 VGPR, loaded ONCE.
// Per step: h (8KB, LDS, B-frag layout) -> 32 MFMAs -> gates -> write h -> barrier.
__global__ __launch_bounds__(1024, 4) void lstm_kernel(
    const int* __restrict__ tokens, const float* __restrict__ embproj,
    const u32x4* __restrict__ whpack, float* __restrict__ out)
{
  const int bid = blockIdx.x;
  const int dir = bid >> 7;
  const int r0  = (bid & 127) << 4;   // 16 batch rows per block
  const int tid = threadIdx.x;
  const int w   = tid >> 6;           // 0..15
  const int l   = tid & 63;
  const int l15 = l & 15;
  const int lg  = l >> 4;

  const float* ep = embproj + dir*131072;   // [128 tok][1024 m]

  // hbuf: h double-buffer in B-frag order [buf][kb][lane][4xu32]; oversized first dim
  // (80KB) + ts pushes block LDS to ~88KB so at most 1 block/CU (forces full-chip spread).
  __shared__ __align__(16) unsigned hbuf[10][8][64][4];
  __shared__ int ts[16][132];               // tokens for this block's 16 rows (+pad: 2-way max)

  for (int i = tid; i < 2048; i += 1024)
    ts[i >> 7][i & 127] = tokens[(r0 + (i >> 7))*128 + (i & 127)];
  {
    unsigned* hz = &hbuf[0][0][0][0];
    for (int i = tid; i < 4096; i += 1024) hz[i] = 0u;   // zero both h buffers
  }
  __syncthreads();

  // load Wh frags into registers (once): W[g][kb], mf_global = g*16 + w
  bf16x8 W[4][8];
  {
    const u32x4* wp = whpack + dir*32768;
    #pragma unroll
    for (int g = 0; g < 4; g++)
      #pragma unroll
      for (int kb = 0; kb < 8; kb++)
        W[g][kb] = *(const bf16x8*)&wp[((g*16 + w)*8 + kb)*64 + l];
  }

  f32x4 c4 = {0.f,0.f,0.f,0.f};   // c,h for (b=r0+l15, u=16w+lg*4+r)
  f32x4 h4 = {0.f,0.f,0.f,0.f};

  for (int t = 0; t < 128; t++){
    const int tcol = dir ? (127 - t) : t;
    const int tok  = ts[l15][tcol];
    const float* gptr = ep + tok*1024 + w*16 + lg*4;
    f32x4 xz[4];                           // issued now, consumed at gate phase
    #pragma unroll
    for (int g = 0; g < 4; g++) xz[g] = *(const f32x4*)(gptr + g*256);

    const int rb = t & 1;
    bf16x8 B[8];
    #pragma unroll
    for (int kb = 0; kb < 8; kb++)
      B[kb] = *(const bf16x8*)&hbuf[rb][kb][l][0];

    f32x4 acc[4];
    #pragma unroll
    for (int g = 0; g < 4; g++) acc[g] = {0.f,0.f,0.f,0.f};
    #pragma unroll
    for (int kb = 0; kb < 8; kb++)
      #pragma unroll
      for (int g = 0; g < 4; g++)
        acc[g] = __builtin_amdgcn_mfma_f32_16x16x32_bf16(W[g][kb], B[kb], acc[g], 0, 0, 0);

    // gates: z = acc + xz; D-frag row = unit offset lg*4+r, col = batch l15
    f32x4 cn, hn;
    #pragma unroll
    for (int r = 0; r < 4; r++){
      const float zi = acc[0][r] + xz[0][r];
      const float zf = acc[1][r] + xz[1][r];
      const float zg = acc[2][r] + xz[2][r];
      const float zo = acc[3][r] + xz[3][r];
      const float cc = sig_f(zf)*c4[r] + sig_f(zi)*tanh_f(zg);
      cn[r] = cc;
      hn[r] = sig_f(zo)*tanh_f(cc);
    }
    c4 = cn; h4 = hn;

    // write h (bf16) into next buffer, B-frag aligned: kb=w>>1, u32 words (w&1)*2..+1
    u32x2 pk;
    pk.x = cvt_pk_bf16(hn[0], hn[1]);
    pk.y = cvt_pk_bf16(hn[2], hn[3]);
    *(u32x2*)&hbuf[rb ^ 1][w >> 1][l][(w & 1)*2] = pk;
    __syncthreads();
  }

  // outputs: output[2048][512], fh@1048576, fc@1572864, bh@2097152, bc@2621440
  const int b  = r0 + l15;
  const int u0 = w*16 + lg*4;
  *(f32x4*)(out + b*512 + dir*256 + u0)               = h4;
  *(f32x4*)(out + 1048576 + dir*1048576 + b*256 + u0) = h4;
  *(f32x4*)(out + 1572864 + dir*1048576 + b*256 + u0) = c4;
}

extern "C" void kernel_launch(void* const* d_in, const int* in_sizes, int n_in,
                              void* d_out, int out_size, void* d_ws, size_t ws_size,
                              hipStream_t stream){
  const int*   tokens = (const int*)  d_in[0];
  const float* emb    = (const float*)d_in[1];
  const float* Wx_f   = (const float*)d_in[2];
  const float* Wh_f   = (const float*)d_in[3];
  const float* b_f    = (const float*)d_in[4];
  const float* Wx_b   = (const float*)d_in[5];
  const float* Wh_b   = (const float*)d_in[6];
  const float* b_b    = (const float*)d_in[7];
  float* out = (float*)d_out;

  // ws: embproj 2*128*1024 f32 (1 MB) | whpack 2*64*8*64 frags * 16B (1 MB)
  float*  embproj = (float*)d_ws;
  u32x4*  whpack  = (u32x4*)(embproj + 262144);

  embproj_kernel<<<1024, 256, 0, stream>>>(emb, Wx_f, b_f, Wx_b, b_b, embproj);
  whpack_kernel<<<256, 256, 0, stream>>>(Wh_f, Wh_b, whpack);
  lstm_kernel<<<256, 1024, 0, stream>>>(tokens, embproj, whpack, out);
}

// Round 4
// 461.212 us; speedup vs baseline: 3.8134x; 2.0221x over previous
//
#include <hip/hip_runtime.h>

typedef __attribute__((ext_vector_type(8))) short bf16x8;
typedef __attribute__((ext_vector_type(4))) float f32x4;
typedef __attribute__((ext_vector_type(2))) unsigned int u32x2;
typedef __attribute__((ext_vector_type(4))) unsigned int u32x4;

__device__ __forceinline__ unsigned cvt_pk_bf16(float lo, float hi){
  unsigned r; asm("v_cvt_pk_bf16_f32 %0, %1, %2" : "=v"(r) : "v"(lo), "v"(hi)); return r;
}
// sigmoid(x) = 1/(1+2^(-x*log2e)); inf-safe at both ends (rcp(inf)=0).
__device__ __forceinline__ float sig_f(float x){
  return __builtin_amdgcn_rcpf(1.f + __builtin_amdgcn_exp2f(-1.442695040888963f*x));
}
// tanh(x) = 1 - 2/(1+2^(2x*log2e)); inf-safe.
__device__ __forceinline__ float tanh_f(float x){
  return 1.f - 2.f*__builtin_amdgcn_rcpf(1.f + __builtin_amdgcn_exp2f(2.885390081777927f*x));
}

// ---------------- prologue 1: embproj[dir][tok][m] = emb[tok]@Wx_dir + b_dir --------------
__global__ void embproj_kernel(const float* __restrict__ emb,
                               const float* __restrict__ Wx_f, const float* __restrict__ b_f,
                               const float* __restrict__ Wx_b, const float* __restrict__ b_b,
                               float* __restrict__ embproj){
  const int blk = blockIdx.x;              // 1024 blocks = 2 dir * 128 tok * 4 chunks
  const int dir = blk >> 9;
  const int tok = (blk >> 2) & 127;
  const int m   = (blk & 3)*256 + threadIdx.x;
  const float* Wx = dir ? Wx_b : Wx_f;
  const float* bb = dir ? b_b  : b_f;
  __shared__ float es[128];
  if (threadIdx.x < 128) es[threadIdx.x] = emb[tok*128 + threadIdx.x];
  __syncthreads();
  float acc = bb[m];
  #pragma unroll 4
  for (int e = 0; e < 128; e++) acc = fmaf(es[e], Wx[e*1024 + m], acc);
  embproj[(dir*128 + tok)*1024 + m] = acc;
}

// ---------------- prologue 2: pack Wh^T into MFMA A-fragment order (bf16) -----------------
// frag layout: [dir][mf(64)][kb(8)][lane(64)] x 16B; lane: m = mf*16+(l&15),
// k-slot j: k = kb*32 + (l>>4)*4 + (j&3) + 16*(j>>2)   (A and B use the same map)
__global__ void whpack_kernel(const float* __restrict__ Wh_f, const float* __restrict__ Wh_b,
                              u32x4* __restrict__ whpack){
  const int t = blockIdx.x*256 + threadIdx.x;  // 65536 threads
  const int lane = t & 63;
  const int kb   = (t >> 6) & 7;
  const int mf   = (t >> 9) & 63;
  const int dir  = t >> 15;
  const float* Wh = dir ? Wh_b : Wh_f;  // [256 k][1024 m]
  const int m = mf*16 + (lane & 15);
  const int kbase = kb*32 + ((lane >> 4) << 2);
  u32x4 o;
  #pragma unroll
  for (int p = 0; p < 4; p++){           // u32 p holds slots j=2p, 2p+1
    const int k0 = kbase + (p & 1)*2 + (p >> 1)*16;
    unsigned pk = cvt_pk_bf16(Wh[k0*1024 + m], Wh[(k0+1)*1024 + m]);
    if (p == 0) o.x = pk; else if (p == 1) o.y = pk; else if (p == 2) o.z = pk; else o.w = pk;
  }
  whpack[t] = o;
}

// ---------------- main: persistent LSTM, W 75% VGPR / 25% LDS -----------------------------
// grid 256 = 2 dir * 128 tiles of 16 batch rows. 512 thr = 8 waves (2/SIMD, 256 VGPR).
// Wave w owns units [32w,32w+32): mf = g*16+2w+q (g=gate, q=0..1), kb=0..7.
//   kb 0..5 -> VGPR-resident (48 frags, 192 regs); kb 6..7 -> LDS (16 frags/wave, 128 KB).
// h lives in LDS B-frag layout; wave w's output IS frag kb=w -> one ds_write_b128/step.
__global__ __launch_bounds__(512, 2) void lstm_kernel(
    const int* __restrict__ tokens, const float* __restrict__ embproj,
    const u32x4* __restrict__ whpack, float* __restrict__ out)
{
  const int bid = blockIdx.x;
  const int dir = bid >> 7;
  const int r0  = (bid & 127) << 4;   // 16 batch rows
  const int tid = threadIdx.x;
  const int w   = tid >> 6;           // 0..7
  const int l   = tid & 63;
  const int l15 = l & 15;
  const int lg  = l >> 4;

  const float* ep = embproj + dir*131072;     // [128 tok][1024 m]
  const u32x4* wp = whpack + dir*32768;

  __shared__ __align__(16) unsigned hbuf[2][8][64][4];   // 16 KB h double-buffer (B-frag)
  __shared__ __align__(16) u32x4 wlds[8][8][2][64];      // 128 KB: [w][g*2+q][kb-6][lane]
  __shared__ int ts[16][132];                            // tokens, padded

  for (int i = tid; i < 2048; i += 512)
    ts[i >> 7][i & 127] = tokens[(r0 + (i >> 7))*128 + (i & 127)];
  for (int i = tid; i < 4096; i += 512) (&hbuf[0][0][0][0])[i] = 0u;
  #pragma unroll
  for (int g = 0; g < 4; g++)
    #pragma unroll
    for (int q = 0; q < 2; q++)
      #pragma unroll
      for (int kbh = 0; kbh < 2; kbh++)
        wlds[w][g*2 + q][kbh][l] = wp[((g*16 + 2*w + q)*8 + 6 + kbh)*64 + l];

  // resident weight frags (loaded once, loop-invariant): 48 frags = 192 VGPR
  bf16x8 W[4][2][6];
  #pragma unroll
  for (int g = 0; g < 4; g++)
    #pragma unroll
    for (int q = 0; q < 2; q++)
      #pragma unroll
      for (int kb = 0; kb < 6; kb++)
        W[g][q][kb] = *(const bf16x8*)&wp[((g*16 + 2*w + q)*8 + kb)*64 + l];
  __syncthreads();

  f32x4 c4[2] = {{0.f,0.f,0.f,0.f},{0.f,0.f,0.f,0.f}};  // c for (b=r0+l15, u=32w+16q+lg*4+r)

  for (int t = 0; t < 128; t++){
    const int tcol = dir ? (127 - t) : t;
    const int tok  = ts[l15][tcol];
    const float* gp = ep + tok*1024 + 32*w + lg*4;

    // acc C-init = xz (issued first; L2-resident)
    f32x4 acc[4][2];
    #pragma unroll
    for (int g = 0; g < 4; g++)
      #pragma unroll
      for (int q = 0; q < 2; q++)
        acc[g][q] = *(const f32x4*)(gp + g*256 + q*16);

    const int rb = t & 1;
    #pragma unroll
    for (int kb = 0; kb < 6; kb++){
      const bf16x8 B = *(const bf16x8*)&hbuf[rb][kb][l][0];
      #pragma unroll
      for (int g = 0; g < 4; g++)
        #pragma unroll
        for (int q = 0; q < 2; q++)
          acc[g][q] = __builtin_amdgcn_mfma_f32_16x16x32_bf16(W[g][q][kb], B, acc[g][q], 0, 0, 0);
    }
    #pragma unroll
    for (int kbh = 0; kbh < 2; kbh++){
      const bf16x8 B = *(const bf16x8*)&hbuf[rb][6 + kbh][l][0];
      #pragma unroll
      for (int g = 0; g < 4; g++)
        #pragma unroll
        for (int q = 0; q < 2; q++){
          const bf16x8 Wl = *(const bf16x8*)&wlds[w][g*2 + q][kbh][l];
          acc[g][q] = __builtin_amdgcn_mfma_f32_16x16x32_bf16(Wl, B, acc[g][q], 0, 0, 0);
        }
    }

    // gates; write h (bf16) -> next buffer frag kb=w (u32x4, one ds_write_b128)
    u32x4 pk;
    #pragma unroll
    for (int q = 0; q < 2; q++){
      f32x4 cn, hn;
      #pragma unroll
      for (int r = 0; r < 4; r++){
        const float zi = acc[0][q][r];
        const float zf = acc[1][q][r];
        const float zg = acc[2][q][r];
        const float zo = acc[3][q][r];
        const float cc = sig_f(zf)*c4[q][r] + sig_f(zi)*tanh_f(zg);
        cn[r] = cc;
        hn[r] = sig_f(zo)*tanh_f(cc);
      }
      c4[q] = cn;
      if (q == 0){ pk.x = cvt_pk_bf16(hn[0], hn[1]); pk.y = cvt_pk_bf16(hn[2], hn[3]); }
      else       { pk.z = cvt_pk_bf16(hn[0], hn[1]); pk.w = cvt_pk_bf16(hn[2], hn[3]); }
      if (t == 127){   // final h -> outputs (uniform branch, executed once)
        const int b  = r0 + l15;
        const int u0 = 32*w + 16*q + lg*4;
        *(f32x4*)(out + b*512 + dir*256 + u0)               = hn;
        *(f32x4*)(out + 1048576 + dir*1048576 + b*256 + u0) = hn;
      }
    }
    *(u32x4*)&hbuf[rb ^ 1][w][l][0] = pk;
    __syncthreads();
  }

  // final c -> outputs
  #pragma unroll
  for (int q = 0; q < 2; q++){
    const int b  = r0 + l15;
    const int u0 = 32*w + 16*q + lg*4;
    *(f32x4*)(out + 1572864 + dir*1048576 + b*256 + u0) = c4[q];
  }
}

extern "C" void kernel_launch(void* const* d_in, const int* in_sizes, int n_in,
                              void* d_out, int out_size, void* d_ws, size_t ws_size,
                              hipStream_t stream){
  const int*   tokens = (const int*)  d_in[0];
  const float* emb    = (const float*)d_in[1];
  const float* Wx_f   = (const float*)d_in[2];
  const float* Wh_f   = (const float*)d_in[3];
  const float* b_f    = (const float*)d_in[4];
  const float* Wx_b   = (const float*)d_in[5];
  const float* Wh_b   = (const float*)d_in[6];
  const float* b_b    = (const float*)d_in[7];
  float* out = (float*)d_out;

  // ws: embproj 2*128*1024 f32 (1 MB) | whpack 2*64*8*64 frags * 16B (1 MB)
  float*  embproj = (float*)d_ws;
  u32x4*  whpack  = (u32x4*)(embproj + 262144);

  embproj_kernel<<<1024, 256, 0, stream>>>(emb, Wx_f, b_f, Wx_b, b_b, embproj);
  whpack_kernel<<<256, 256, 0, stream>>>(Wh_f, Wh_b, whpack);
  lstm_kernel<<<256, 512, 0, stream>>>(tokens, embproj, whpack, out);
}

// Round 5
// 455.850 us; speedup vs baseline: 3.8582x; 1.0118x over previous
//
#include <hip/hip_runtime.h>

typedef __attribute__((ext_vector_type(8))) short bf16x8;
typedef __attribute__((ext_vector_type(4))) float f32x4;
typedef __attribute__((ext_vector_type(2))) unsigned int u32x2;
typedef __attribute__((ext_vector_type(4))) unsigned int u32x4;

#define LOG2E  1.442695040888963f
#define LOG2E2 2.885390081777927f

__device__ __forceinline__ unsigned cvt_pk_bf16(float lo, float hi){
  unsigned r; asm("v_cvt_pk_bf16_f32 %0, %1, %2" : "=v"(r) : "v"(lo), "v"(hi)); return r;
}
// z already scaled by log2e: sigmoid(x) = rcp(1+2^(-z))
__device__ __forceinline__ float sig_p(float z){
  return __builtin_amdgcn_rcpf(1.f + __builtin_amdgcn_exp2f(-z));
}
// z already scaled by 2*log2e: tanh(x) = 1 - 2*rcp(1+2^z)
__device__ __forceinline__ float tanhg_p(float z){
  return 1.f - 2.f*__builtin_amdgcn_rcpf(1.f + __builtin_amdgcn_exp2f(z));
}
// natural-domain tanh (for c)
__device__ __forceinline__ float tanh_f(float x){
  return 1.f - 2.f*__builtin_amdgcn_rcpf(1.f + __builtin_amdgcn_exp2f(LOG2E2*x));
}

// ---------------- prologue 1: embproj[dir][tok][m] = (emb[tok]@Wx + b) * gate_scale ------
__global__ void embproj_kernel(const float* __restrict__ emb,
                               const float* __restrict__ Wx_f, const float* __restrict__ b_f,
                               const float* __restrict__ Wx_b, const float* __restrict__ b_b,
                               float* __restrict__ embproj){
  const int blk = blockIdx.x;              // 1024 blocks = 2 dir * 128 tok * 4 chunks
  const int dir = blk >> 9;
  const int tok = (blk >> 2) & 127;
  const int m   = (blk & 3)*256 + threadIdx.x;
  const float* Wx = dir ? Wx_b : Wx_f;
  const float* bb = dir ? b_b  : b_f;
  __shared__ float es[128];
  if (threadIdx.x < 128) es[threadIdx.x] = emb[tok*128 + threadIdx.x];
  __syncthreads();
  float acc = bb[m];
  #pragma unroll 4
  for (int e = 0; e < 128; e++) acc = fmaf(es[e], Wx[e*1024 + m], acc);
  const float s = ((m >> 8) == 2) ? LOG2E2 : LOG2E;   // g-gate gets 2*log2e
  embproj[(dir*128 + tok)*1024 + m] = acc * s;
}

// ---------------- prologue 2: pack Wh^T into MFMA A-fragment order (bf16), pre-scaled -----
// frag layout: [dir][mf(64)][kb(8)][lane(64)] x 16B; lane: m = mf*16+(l&15),
// k-slot j: k = kb*32 + (l>>4)*4 + (j&3) + 16*(j>>2)   (A and B use the same map)
__global__ void whpack_kernel(const float* __restrict__ Wh_f, const float* __restrict__ Wh_b,
                              u32x4* __restrict__ whpack){
  const int t = blockIdx.x*256 + threadIdx.x;  // 65536 threads
  const int lane = t & 63;
  const int kb   = (t >> 6) & 7;
  const int mf   = (t >> 9) & 63;
  const int dir  = t >> 15;
  const float* Wh = dir ? Wh_b : Wh_f;  // [256 k][1024 m]
  const int m = mf*16 + (lane & 15);
  const int kbase = kb*32 + ((lane >> 4) << 2);
  const float s = ((mf >> 4) == 2) ? LOG2E2 : LOG2E;
  u32x4 o;
  #pragma unroll
  for (int p = 0; p < 4; p++){           // u32 p holds slots j=2p, 2p+1
    const int k0 = kbase + (p & 1)*2 + (p >> 1)*16;
    unsigned pk = cvt_pk_bf16(Wh[k0*1024 + m]*s, Wh[(k0+1)*1024 + m]*s);
    if (p == 0) o.x = pk; else if (p == 1) o.y = pk; else if (p == 2) o.z = pk; else o.w = pk;
  }
  whpack[t] = o;
}

// ---------------- main: persistent LSTM, W 75% VGPR / 25% LDS -----------------------------
// grid 256 = 2 dir * 128 tiles of 16 batch rows. 512 thr = 8 waves (2/SIMD).
// Wave w owns units [32w,32w+32): mf = g*16+2w+q, kb=0..7.
//   kb 0..5 VGPR/AGPR-resident (48 frags); kb 6..7 in LDS (16 frags/wave, 128 KB).
// Step: [tok prefetch | xz loads | B+Wl ds burst] -> MFMA (acc=0 C-init) -> gates(+xz) ->
// h ds_write (frag kb=w) -> barrier. xz latency hides under MFMA phase.
__global__ __launch_bounds__(512, 2) void lstm_kernel(
    const int* __restrict__ tokens, const float* __restrict__ embproj,
    const u32x4* __restrict__ whpack, float* __restrict__ out)
{
  const int bid = blockIdx.x;
  const int dir = bid >> 7;
  const int r0  = (bid & 127) << 4;   // 16 batch rows
  const int tid = threadIdx.x;
  const int w   = tid >> 6;           // 0..7
  const int l   = tid & 63;
  const int l15 = l & 15;
  const int lg  = l >> 4;

  const float* ep = embproj + dir*131072;     // [128 tok][1024 m]
  const u32x4* wp = whpack + dir*32768;

  __shared__ __align__(16) unsigned hbuf[2][8][64][4];   // 16 KB h double-buffer (B-frag)
  __shared__ __align__(16) u32x4 wlds[8][8][2][64];      // 128 KB: [w][g*2+q][kb-6][lane]
  __shared__ int ts[16][132];                            // tokens, padded (2-way max)

  for (int i = tid; i < 2048; i += 512)
    ts[i >> 7][i & 127] = tokens[(r0 + (i >> 7))*128 + (i & 127)];
  for (int i = tid; i < 4096; i += 512) (&hbuf[0][0][0][0])[i] = 0u;
  #pragma unroll
  for (int g = 0; g < 4; g++)
    #pragma unroll
    for (int q = 0; q < 2; q++)
      #pragma unroll
      for (int kbh = 0; kbh < 2; kbh++)
        wlds[w][g*2 + q][kbh][l] = wp[((g*16 + 2*w + q)*8 + 6 + kbh)*64 + l];

  // resident weight frags (loaded once, loop-invariant): 48 frags
  bf16x8 W[4][2][6];
  #pragma unroll
  for (int g = 0; g < 4; g++)
    #pragma unroll
    for (int q = 0; q < 2; q++)
      #pragma unroll
      for (int kb = 0; kb < 6; kb++)
        W[g][q][kb] = *(const bf16x8*)&wp[((g*16 + 2*w + q)*8 + kb)*64 + l];
  __syncthreads();

  f32x4 c4[2] = {{0.f,0.f,0.f,0.f},{0.f,0.f,0.f,0.f}};  // c for (b=r0+l15, u=32w+16q+lg*4+r)
  int tok_cur = ts[l15][dir ? 127 : 0];

  for (int t = 0; t < 128; t++){
    // token prefetch for t+1 (ds_read overlaps everything below)
    const int tn    = (t < 127) ? t + 1 : 127;
    const int tok_n = ts[l15][dir ? (127 - tn) : tn];

    // xz loads issued now, consumed only at gate phase (z = acc + xz)
    const float* gp = ep + tok_cur*1024 + 32*w + lg*4;
    f32x4 xz[4][2];
    #pragma unroll
    for (int g = 0; g < 4; g++)
      #pragma unroll
      for (int q = 0; q < 2; q++)
        xz[g][q] = *(const f32x4*)(gp + g*256 + q*16);

    const int rb = t & 1;
    // burst-issue LDS reads: all B frags + first half of LDS-resident W
    bf16x8 B[8];
    #pragma unroll
    for (int kb = 0; kb < 8; kb++)
      B[kb] = *(const bf16x8*)&hbuf[rb][kb][l][0];
    bf16x8 WlA[8];
    #pragma unroll
    for (int f = 0; f < 8; f++) WlA[f] = *(const bf16x8*)&wlds[w][f][0][l];

    f32x4 acc[4][2];
    #pragma unroll
    for (int g = 0; g < 4; g++)
      #pragma unroll
      for (int q = 0; q < 2; q++)
        acc[g][q] = {0.f,0.f,0.f,0.f};

    #pragma unroll
    for (int kb = 0; kb < 3; kb++)
      #pragma unroll
      for (int g = 0; g < 4; g++)
        #pragma unroll
        for (int q = 0; q < 2; q++)
          acc[g][q] = __builtin_amdgcn_mfma_f32_16x16x32_bf16(W[g][q][kb], B[kb], acc[g][q], 0, 0, 0);

    bf16x8 WlB[8];
    #pragma unroll
    for (int f = 0; f < 8; f++) WlB[f] = *(const bf16x8*)&wlds[w][f][1][l];

    #pragma unroll
    for (int kb = 3; kb < 6; kb++)
      #pragma unroll
      for (int g = 0; g < 4; g++)
        #pragma unroll
        for (int q = 0; q < 2; q++)
          acc[g][q] = __builtin_amdgcn_mfma_f32_16x16x32_bf16(W[g][q][kb], B[kb], acc[g][q], 0, 0, 0);
    #pragma unroll
    for (int g = 0; g < 4; g++)
      #pragma unroll
      for (int q = 0; q < 2; q++)
        acc[g][q] = __builtin_amdgcn_mfma_f32_16x16x32_bf16(WlA[g*2 + q], B[6], acc[g][q], 0, 0, 0);
    #pragma unroll
    for (int g = 0; g < 4; g++)
      #pragma unroll
      for (int q = 0; q < 2; q++)
        acc[g][q] = __builtin_amdgcn_mfma_f32_16x16x32_bf16(WlB[g*2 + q], B[7], acc[g][q], 0, 0, 0);

    // gates (z pre-scaled by log2e / 2log2e); write h (bf16) -> next buffer frag kb=w
    u32x4 pk;
    #pragma unroll
    for (int q = 0; q < 2; q++){
      f32x4 cn, hn;
      #pragma unroll
      for (int r = 0; r < 4; r++){
        const float zi = acc[0][q][r] + xz[0][q][r];
        const float zf = acc[1][q][r] + xz[1][q][r];
        const float zg = acc[2][q][r] + xz[2][q][r];
        const float zo = acc[3][q][r] + xz[3][q][r];
        const float cc = sig_p(zf)*c4[q][r] + sig_p(zi)*tanhg_p(zg);
        cn[r] = cc;
        hn[r] = sig_p(zo)*tanh_f(cc);
      }
      c4[q] = cn;
      if (q == 0){ pk.x = cvt_pk_bf16(hn[0], hn[1]); pk.y = cvt_pk_bf16(hn[2], hn[3]); }
      else       { pk.z = cvt_pk_bf16(hn[0], hn[1]); pk.w = cvt_pk_bf16(hn[2], hn[3]); }
      if (t == 127){   // final h -> outputs (uniform branch)
        const int b  = r0 + l15;
        const int u0 = 32*w + 16*q + lg*4;
        *(f32x4*)(out + b*512 + dir*256 + u0)               = hn;
        *(f32x4*)(out + 1048576 + dir*1048576 + b*256 + u0) = hn;
      }
    }
    *(u32x4*)&hbuf[rb ^ 1][w][l][0] = pk;
    tok_cur = tok_n;
    __syncthreads();
  }

  // final c -> outputs
  #pragma unroll
  for (int q = 0; q < 2; q++){
    const int b  = r0 + l15;
    const int u0 = 32*w + 16*q + lg*4;
    *(f32x4*)(out + 1572864 + dir*1048576 + b*256 + u0) = c4[q];
  }
}

extern "C" void kernel_launch(void* const* d_in, const int* in_sizes, int n_in,
                              void* d_out, int out_size, void* d_ws, size_t ws_size,
                              hipStream_t stream){
  const int*   tokens = (const int*)  d_in[0];
  const float* emb    = (const float*)d_in[1];
  const float* Wx_f   = (const float*)d_in[2];
  const float* Wh_f   = (const float*)d_in[3];
  const float* b_f    = (const float*)d_in[4];
  const float* Wx_b   = (const float*)d_in[5];
  const float* Wh_b   = (const float*)d_in[6];
  const float* b_b    = (const float*)d_in[7];
  float* out = (float*)d_out;

  // ws: embproj 2*128*1024 f32 (1 MB) | whpack 2*64*8*64 frags * 16B (1 MB)
  float*  embproj = (float*)d_ws;
  u32x4*  whpack  = (u32x4*)(embproj + 262144);

  embproj_kernel<<<1024, 256, 0, stream>>>(emb, Wx_f, b_f, Wx_b, b_b, embproj);
  whpack_kernel<<<256, 256, 0, stream>>>(Wh_f, Wh_b, whpack);
  lstm_kernel<<<256, 512, 0, stream>>>(tokens, embproj, whpack, out);
}

// Round 7
// 400.812 us; speedup vs baseline: 4.3880x; 1.1373x over previous
//
#include <hip/hip_runtime.h>

typedef __attribute__((ext_vector_type(8))) short bf16x8;
typedef __attribute__((ext_vector_type(4))) float f32x4;
typedef __attribute__((ext_vector_type(2))) unsigned int u32x2;
typedef __attribute__((ext_vector_type(4))) unsigned int u32x4;

#define LOG2E  1.442695040888963f
#define LOG2E2 2.885390081777927f

__device__ __forceinline__ unsigned cvt_pk_bf16(float lo, float hi){
  unsigned r; asm("v_cvt_pk_bf16_f32 %0, %1, %2" : "=v"(r) : "v"(lo), "v"(hi)); return r;
}
// z already scaled by log2e: sigmoid(x) = rcp(1+2^(-z))
__device__ __forceinline__ float sig_p(float z){
  return __builtin_amdgcn_rcpf(1.f + __builtin_amdgcn_exp2f(-z));
}
// z already scaled by 2*log2e: tanh(x) = 1 - 2*rcp(1+2^z)
__device__ __forceinline__ float tanhg_p(float z){
  return 1.f - 2.f*__builtin_amdgcn_rcpf(1.f + __builtin_amdgcn_exp2f(z));
}
// natural-domain tanh (for c)
__device__ __forceinline__ float tanh_f(float x){
  return 1.f - 2.f*__builtin_amdgcn_rcpf(1.f + __builtin_amdgcn_exp2f(LOG2E2*x));
}

// ---------------- prologue 1: embproj[dir][tok][m] = (emb[tok]@Wx + b) * gate_scale ------
__global__ void embproj_kernel(const float* __restrict__ emb,
                               const float* __restrict__ Wx_f, const float* __restrict__ b_f,
                               const float* __restrict__ Wx_b, const float* __restrict__ b_b,
                               float* __restrict__ embproj){
  const int blk = blockIdx.x;              // 1024 blocks = 2 dir * 128 tok * 4 chunks
  const int dir = blk >> 9;
  const int tok = (blk >> 2) & 127;
  const int m   = (blk & 3)*256 + threadIdx.x;
  const float* Wx = dir ? Wx_b : Wx_f;
  const float* bb = dir ? b_b  : b_f;
  __shared__ float es[128];
  if (threadIdx.x < 128) es[threadIdx.x] = emb[tok*128 + threadIdx.x];
  __syncthreads();
  float acc = bb[m];
  #pragma unroll 4
  for (int e = 0; e < 128; e++) acc = fmaf(es[e], Wx[e*1024 + m], acc);
  const float s = ((m >> 8) == 2) ? LOG2E2 : LOG2E;   // g-gate gets 2*log2e
  embproj[(dir*128 + tok)*1024 + m] = acc * s;
}

// ---------------- prologue 2: pack Wh^T into MFMA A-fragment order (bf16), pre-scaled -----
// frag layout: [dir][mf(64)][kb(8)][lane(64)] x 16B; lane: m = mf*16+(l&15),
// k-slot j: k = kb*32 + (l>>4)*4 + (j&3) + 16*(j>>2)   (A and B use the same map)
__global__ void whpack_kernel(const float* __restrict__ Wh_f, const float* __restrict__ Wh_b,
                              u32x4* __restrict__ whpack){
  const int t = blockIdx.x*256 + threadIdx.x;  // 65536 threads
  const int lane = t & 63;
  const int kb   = (t >> 6) & 7;
  const int mf   = (t >> 9) & 63;
  const int dir  = t >> 15;
  const float* Wh = dir ? Wh_b : Wh_f;  // [256 k][1024 m]
  const int m = mf*16 + (lane & 15);
  const int kbase = kb*32 + ((lane >> 4) << 2);
  const float s = ((mf >> 4) == 2) ? LOG2E2 : LOG2E;
  u32x4 o;
  #pragma unroll
  for (int p = 0; p < 4; p++){           // u32 p holds slots j=2p, 2p+1
    const int k0 = kbase + (p & 1)*2 + (p >> 1)*16;
    unsigned pk = cvt_pk_bf16(Wh[k0*1024 + m]*s, Wh[(k0+1)*1024 + m]*s);
    if (p == 0) o.x = pk; else if (p == 1) o.y = pk; else if (p == 2) o.z = pk; else o.w = pk;
  }
  whpack[t] = o;
}

// ---------------- main: persistent LSTM ---------------------------------------------------
// grid 256 = 2 dir * 128 tiles of 16 batch rows. 512 thr = 8 waves (2/SIMD, 256 unified regs).
// Wave w owns units [32w,32w+32): frag f=g*2+q -> mf=(f>>1)*16+2w+(f&1).
//   kb 0..3: AGPR-resident (32 frags, 128 regs)    kb 4..5: L2-streamed (one reused window)
//   kb 6..7: LDS (16 frags/wave, 128 KB), 4-frag JIT windows
// Sync: ds_write h -> s_waitcnt lgkmcnt(0) -> s_barrier (NO vmcnt drain: xz/W-stream loads
// stay in flight across the barrier — the round-4/5 __syncthreads drain was the stall).
__global__ __launch_bounds__(512, 2) void lstm_kernel(
    const int* __restrict__ tokens, const float* __restrict__ embproj,
    const u32x4* __restrict__ whpack, float* __restrict__ out)
{
  const int bid = blockIdx.x;
  const int dir = bid >> 7;
  const int r0  = (bid & 127) << 4;   // 16 batch rows
  const int tid = threadIdx.x;
  const int w   = tid >> 6;           // 0..7
  const int l   = tid & 63;
  const int l15 = l & 15;
  const int lg  = l >> 4;

  const float* ep = embproj + dir*131072;     // [128 tok][1024 m]
  const u32x4* wp = whpack + dir*32768;

  __shared__ __align__(16) unsigned hbuf[2][8][64][4];   // 16 KB h double-buffer (B-frag)
  __shared__ __align__(16) u32x4 wlds[8][8][2][64];      // 128 KB: [w][f][kb-6][lane]
  __shared__ int ts[16][132];                            // tokens, padded

  for (int i = tid; i < 2048; i += 512)
    ts[i >> 7][i & 127] = tokens[(r0 + (i >> 7))*128 + (i & 127)];
  for (int i = tid; i < 4096; i += 512) (&hbuf[0][0][0][0])[i] = 0u;
  #pragma unroll
  for (int f = 0; f < 8; f++)
    #pragma unroll
    for (int kbh = 0; kbh < 2; kbh++)
      wlds[w][f][kbh][l] = wp[(((f >> 1)*16 + 2*w + (f & 1))*8 + 6 + kbh)*64 + l];

  // resident weight frags kb 0..3 (32 frags = 128 regs, loaded once)
  bf16x8 Wr[8][4];
  #pragma unroll
  for (int f = 0; f < 8; f++)
    #pragma unroll
    for (int kb = 0; kb < 4; kb++)
      Wr[f][kb] = *(const bf16x8*)&wp[(((f >> 1)*16 + 2*w + (f & 1))*8 + kb)*64 + l];
  __syncthreads();

  f32x4 c4[2] = {{0.f,0.f,0.f,0.f},{0.f,0.f,0.f,0.f}};  // c for (b=r0+l15, u=32w+16q+lg*4+r)

  // prologue: xz(0) -> acc (C-init)
  f32x4 acc[8];   // f = g*2+q
  {
    const int tok0 = ts[l15][dir ? 127 : 0];
    const float* gp = ep + tok0*1024 + 32*w + lg*4;
    #pragma unroll
    for (int f = 0; f < 8; f++)
      acc[f] = *(const f32x4*)(gp + (f >> 1)*256 + (f & 1)*16);
  }

  for (int t = 0; t < 128; t++){
    const int tn    = (t < 127) ? t + 1 : 127;
    const int tok_n = ts[l15][dir ? (127 - tn) : tn];
    const int rb = t & 1;

    // kb4 stream from L2 (consumed ~40 MFMAs later; window reused for kb5 after)
    bf16x8 Wg[8];
    #pragma unroll
    for (int f = 0; f < 8; f++)
      Wg[f] = *(const bf16x8*)&wp[(((f >> 1)*16 + 2*w + (f & 1))*8 + 4)*64 + l];

    bf16x8 B0 = *(const bf16x8*)&hbuf[rb][0][l][0];
    bf16x8 B1 = *(const bf16x8*)&hbuf[rb][1][l][0];
    bf16x8 B2 = *(const bf16x8*)&hbuf[rb][2][l][0];
    #pragma unroll
    for (int f = 0; f < 8; f++)
      acc[f] = __builtin_amdgcn_mfma_f32_16x16x32_bf16(Wr[f][0], B0, acc[f], 0, 0, 0);

    bf16x8 B3 = *(const bf16x8*)&hbuf[rb][3][l][0];
    #pragma unroll
    for (int f = 0; f < 8; f++)
      acc[f] = __builtin_amdgcn_mfma_f32_16x16x32_bf16(Wr[f][1], B1, acc[f], 0, 0, 0);

    bf16x8 B4 = *(const bf16x8*)&hbuf[rb][4][l][0];
    bf16x8 WlA0[4];
    #pragma unroll
    for (int j = 0; j < 4; j++) WlA0[j] = *(const bf16x8*)&wlds[w][j][0][l];
    #pragma unroll
    for (int f = 0; f < 8; f++)
      acc[f] = __builtin_amdgcn_mfma_f32_16x16x32_bf16(Wr[f][2], B2, acc[f], 0, 0, 0);

    bf16x8 B5 = *(const bf16x8*)&hbuf[rb][5][l][0];
    bf16x8 WlA1[4];
    #pragma unroll
    for (int j = 0; j < 4; j++) WlA1[j] = *(const bf16x8*)&wlds[w][4 + j][0][l];
    #pragma unroll
    for (int f = 0; f < 8; f++)
      acc[f] = __builtin_amdgcn_mfma_f32_16x16x32_bf16(Wr[f][3], B3, acc[f], 0, 0, 0);

    bf16x8 B6 = *(const bf16x8*)&hbuf[rb][6][l][0];
    bf16x8 WlB0[4];
    #pragma unroll
    for (int j = 0; j < 4; j++) WlB0[j] = *(const bf16x8*)&wlds[w][j][1][l];
    // kb4 (streamed, issued at step top)
    #pragma unroll
    for (int f = 0; f < 8; f++)
      acc[f] = __builtin_amdgcn_mfma_f32_16x16x32_bf16(Wg[f], B4, acc[f], 0, 0, 0);

    // reuse window: kb5 stream (consumed after kb6/kb7 groups)
    #pragma unroll
    for (int f = 0; f < 8; f++)
      Wg[f] = *(const bf16x8*)&wp[(((f >> 1)*16 + 2*w + (f & 1))*8 + 5)*64 + l];

    bf16x8 B7 = *(const bf16x8*)&hbuf[rb][7][l][0];
    bf16x8 WlB1[4];
    #pragma unroll
    for (int j = 0; j < 4; j++) WlB1[j] = *(const bf16x8*)&wlds[w][4 + j][1][l];
    // kb6 (LDS)
    #pragma unroll
    for (int f = 0; f < 4; f++)
      acc[f] = __builtin_amdgcn_mfma_f32_16x16x32_bf16(WlA0[f], B6, acc[f], 0, 0, 0);
    #pragma unroll
    for (int f = 4; f < 8; f++)
      acc[f] = __builtin_amdgcn_mfma_f32_16x16x32_bf16(WlA1[f - 4], B6, acc[f], 0, 0, 0);
    // kb7 (LDS)
    #pragma unroll
    for (int f = 0; f < 4; f++)
      acc[f] = __builtin_amdgcn_mfma_f32_16x16x32_bf16(WlB0[f], B7, acc[f], 0, 0, 0);
    #pragma unroll
    for (int f = 4; f < 8; f++)
      acc[f] = __builtin_amdgcn_mfma_f32_16x16x32_bf16(WlB1[f - 4], B7, acc[f], 0, 0, 0);
    // kb5 (streamed)
    #pragma unroll
    for (int f = 0; f < 8; f++)
      acc[f] = __builtin_amdgcn_mfma_f32_16x16x32_bf16(Wg[f], B5, acc[f], 0, 0, 0);

    // gates; xz(t+1) prefetch drops into freed acc regs; h -> hbuf frag kb=w
    const float* gpn = ep + tok_n*1024 + 32*w + lg*4;
    u32x4 pk;
    #pragma unroll
    for (int q = 0; q < 2; q++){
      const f32x4 ai = acc[0 + q], af = acc[2 + q], ag = acc[4 + q], ao = acc[6 + q];
      acc[0 + q] = *(const f32x4*)(gpn + 0*256 + q*16);   // xz(t+1) C-init
      acc[2 + q] = *(const f32x4*)(gpn + 1*256 + q*16);
      acc[4 + q] = *(const f32x4*)(gpn + 2*256 + q*16);
      acc[6 + q] = *(const f32x4*)(gpn + 3*256 + q*16);
      f32x4 cn, hn;
      #pragma unroll
      for (int r = 0; r < 4; r++){
        const float cc = sig_p(af[r])*c4[q][r] + sig_p(ai[r])*tanhg_p(ag[r]);
        cn[r] = cc;
        hn[r] = sig_p(ao[r])*tanh_f(cc);
      }
      c4[q] = cn;
      if (q == 0){ pk.x = cvt_pk_bf16(hn[0], hn[1]); pk.y = cvt_pk_bf16(hn[2], hn[3]); }
      else       { pk.z = cvt_pk_bf16(hn[0], hn[1]); pk.w = cvt_pk_bf16(hn[2], hn[3]); }
      if (t == 127){   // final h -> outputs (uniform branch)
        const int b  = r0 + l15;
        const int u0 = 32*w + 16*q + lg*4;
        *(f32x4*)(out + b*512 + dir*256 + u0)               = hn;
        *(f32x4*)(out + 1048576 + dir*1048576 + b*256 + u0) = hn;
      }
    }
    *(u32x4*)&hbuf[rb ^ 1][w][l][0] = pk;
    // T4 barrier: drain LDS only (own reads+write), leave global loads in flight
    asm volatile("s_waitcnt lgkmcnt(0)" ::: "memory");
    __builtin_amdgcn_s_barrier();
    __builtin_amdgcn_sched_barrier(0);
  }

  // final c -> outputs
  #pragma unroll
  for (int q = 0; q < 2; q++){
    const int b  = r0 + l15;
    const int u0 = 32*w + 16*q + lg*4;
    *(f32x4*)(out + 1572864 + dir*1048576 + b*256 + u0) = c4[q];
  }
}

extern "C" void kernel_launch(void* const* d_in, const int* in_sizes, int n_in,
                              void* d_out, int out_size, void* d_ws, size_t ws_size,
                              hipStream_t stream){
  const int*   tokens = (const int*)  d_in[0];
  const float* emb    = (const float*)d_in[1];
  const float* Wx_f   = (const float*)d_in[2];
  const float* Wh_f   = (const float*)d_in[3];
  const float* b_f    = (const float*)d_in[4];
  const float* Wx_b   = (const float*)d_in[5];
  const float* Wh_b   = (const float*)d_in[6];
  const float* b_b    = (const float*)d_in[7];
  float* out = (float*)d_out;

  // ws: embproj 2*128*1024 f32 (1 MB) | whpack 2*64*8*64 frags * 16B (1 MB)
  float*  embproj = (float*)d_ws;
  u32x4*  whpack  = (u32x4*)(embproj + 262144);

  embproj_kernel<<<1024, 256, 0, stream>>>(emb, Wx_f, b_f, Wx_b, b_b, embproj);
  whpack_kernel<<<256, 256, 0, stream>>>(Wh_f, Wh_b, whpack);
  lstm_kernel<<<256, 512, 0, stream>>>(tokens, embproj, whpack, out);
}